// Round 10
// baseline (51.085 us; speedup 1.0000x reference)
//
#include <hip/hip_runtime.h>

// Problem constants (match reference)
#define BATCH 256
#define PTS   4096
#define HH    512
#define WW    512

#define ROWS_PER_TILE 8
#define TILES (HH / ROWS_PER_TILE)       // 64 tiles (bins) per batch
#define TILE_ELEMS (ROWS_PER_TILE * WW)  // 4096 floats = 16 KB LDS

typedef float f32x4 __attribute__((ext_vector_type(4)));

// ws layout:
//   entries: BATCH*PTS uint2 (pos-in-tile, val bits) = 8 MB  @ ws + 0
//   meta   : BATCH*TILES uint2 (offset, count)       = 128 KB
#define ENTRIES_BYTES ((size_t)BATCH * PTS * 8)

// R9 structure (best: 50.1 us) with 16 KB tiles: 8 blocks/CU resident
// (wave-limited max) so store bursts from other blocks hide each
// block's zero->apply->barrier prelude. Binned CSR -> K2 reads each
// entry byte exactly once (no scan working set for the plain-store
// stream to thrash; R8 showed that's what kills plain stores).

// K1: one block per batch. Scan the point list ONCE, build a per-batch
// CSR binned by 8-row tile. Batch->XCD mapping matches K2 so entries
// are produced and consumed through the same L2.
__global__ __launch_bounds__(1024) void bin_kernel(
        const int* __restrict__ indices,      // [B, P, 2] int32
        const int* __restrict__ num_valid,    // [B] int32
        const float* __restrict__ feats,      // [B, P, 1] f32
        uint2* __restrict__ entries,          // [B, P]
        uint2* __restrict__ meta)             // [B, TILES] (offset, count)
{
    __shared__ unsigned cnt[TILES];
    __shared__ unsigned cur[TILES];

    // Same XCD ownership as K2: XCD x owns batches [x*32, x*32+32).
    int i = blockIdx.x;
    int b = (i & 7) * (BATCH / 8) + (i >> 3);
    int tidx = threadIdx.x;
    if (tidx < TILES) cnt[tidx] = 0;
    int nv = num_valid[b];
    __syncthreads();

    const int2* idx2 = reinterpret_cast<const int2*>(indices) + (size_t)b * PTS;

    // Pass A: count points per 8-row tile (64 LDS counters).
    for (int p = tidx; p < nv; p += 1024)
        atomicAdd(&cnt[((unsigned)idx2[p].x) >> 3], 1u);
    __syncthreads();

    // Exclusive prefix over 64 elements (thread 0, negligible).
    if (tidx == 0) {
        unsigned run = 0;
        for (int k = 0; k < TILES; ++k) { cur[k] = run; run += cnt[k]; }
    }
    __syncthreads();

    if (tidx < TILES)
        meta[b * TILES + tidx] = make_uint2(cur[tidx], cnt[tidx]);
    __syncthreads();   // meta captured before pass B mutates cur[]

    // Pass B: re-scan (L1/L2-hot) and write entries at exact positions.
    const float* fb = feats + (size_t)b * PTS;
    uint2* eb = entries + (size_t)b * PTS;
    for (int p = tidx; p < nv; p += 1024) {
        int2 ij = idx2[p];
        float v = fb[p];
        unsigned bin = ((unsigned)ij.x) >> 3;
        unsigned pos = atomicAdd(&cur[bin], 1u);   // absolute within batch
        eb[pos] = make_uint2((unsigned)((ij.x & (ROWS_PER_TILE - 1)) * WW + ij.y),
                             __float_as_uint(v));
    }
}

// K2: one block per (batch, tile). Zero 16 KB LDS, apply ~32 binned
// entries (contiguous read-once), write the tile once with plain
// dwordx4 stores (dirty-eviction path, the 6.9 TB/s rocclr-fill path).
__global__ __launch_bounds__(256) void tile_write_kernel(
        const uint2* __restrict__ entries,
        const uint2* __restrict__ meta,
        float* __restrict__ out)              // [B, H, W] f32
{
    __shared__ float tile[TILE_ELEMS];

    // XCD-aware remap: each XCD owns 32 whole batches (all 64 tiles).
    int i = blockIdx.x;                       // [0, 16384)
    int xcd  = i & 7;
    int slot = i >> 3;                        // [0, 2048)
    int b = xcd * (BATCH / 8) + (slot >> 6);
    int t = slot & (TILES - 1);
    int tidx = threadIdx.x;

    // One 8B load for (offset, count); issued before the LDS zero so
    // the dependent entry loads start during the zeroing.
    uint2 m = meta[b * TILES + t];

    f32x4* tile4 = reinterpret_cast<f32x4*>(tile);
    #pragma unroll
    for (int k = tidx; k < TILE_ELEMS / 4; k += 256)
        tile4[k] = (f32x4){0.f, 0.f, 0.f, 0.f};
    __syncthreads();

    const uint2* eb = entries + (size_t)b * PTS + m.x;
    for (unsigned e = tidx; e < m.y; e += 256) {
        uint2 ent = eb[e];
        atomicAdd(&tile[ent.x], __uint_as_float(ent.y));
    }
    __syncthreads();

    // Plain stores: full-line contiguous, dirty lines aggregate in L2
    // and stream out via eviction.
    float* ob = out + (size_t)b * (HH * WW) + (size_t)t * TILE_ELEMS;
    f32x4* dst = reinterpret_cast<f32x4*>(ob);
    #pragma unroll
    for (int k = tidx; k < TILE_ELEMS / 4; k += 256)
        dst[k] = tile4[k];
}

extern "C" void kernel_launch(void* const* d_in, const int* in_sizes, int n_in,
                              void* d_out, int out_size, void* d_ws, size_t ws_size,
                              hipStream_t stream) {
    const int*   indices   = (const int*)d_in[0];
    const int*   num_valid = (const int*)d_in[1];
    const float* feats     = (const float*)d_in[2];
    float*       out       = (float*)d_out;

    uint2* entries = (uint2*)d_ws;
    uint2* meta    = (uint2*)((char*)d_ws + ENTRIES_BYTES);

    bin_kernel<<<BATCH, 1024, 0, stream>>>(indices, num_valid, feats,
                                           entries, meta);
    tile_write_kernel<<<BATCH * TILES, 256, 0, stream>>>(entries, meta, out);
}